// Round 15
// baseline (106.615 us; speedup 1.0000x reference)
//
#include <hip/hip_runtime.h>
#include <math.h>

// Problem constants (from reference setup_inputs)
#define BS 32
#define CH 3
#define HH 512
#define WW 512
#define HWSZ (HH * WW)          // 262144
#define MOMENTUM 0.8
#define EPSILON 1e-5

typedef float f32x4 __attribute__((ext_vector_type(4)));

// ---------------- stats kernel (r10-proven, symmetric, interleaved) ----------------
// S1[c] = sum_b x[b,c,0,0]
// S2[c] = sum_{b,h,w} x^2
// S3[c] = sum_{b,h,w} x[h,w] * x[(-h)%H, (-w)%W]
//
// Index math (verified r8..r13): for aligned f4 at o, partners of o+1..o+3
// are .w,.z,.y of f4 at q1=(HWSZ+508-o)&mask; partner of o is .x of f4 at
// q2=(HWSZ+(w0?0:512)-o)&mask, w0=(o%512==0).
// Symmetry (verified r10): A-rows 0..255; h>=1 factor 2, partner-row s2 via
// p1^2; h==0 factor 1, no partner-square; row 256 self-paired tail (blk 0).
// LAYOUT RULE (r14 lesson): lane-adjacent must be address-adjacent — threads
// interleave f4s (idx = tid + step*256), NOT per-thread runs. Batching is
// BATCH=4 triples issued before consumption (r9-proven).

constexpr int BPP = 16;
constexpr int ROWS_PER_BLK = 16;
constexpr int STAT_THREADS = 256;
constexpr int F4_PER_THREAD = ROWS_PER_BLK * (WW / 4) / STAT_THREADS;  // 8
constexpr int BATCH = 4;
constexpr int NBATCH = F4_PER_THREAD / BATCH;  // 2
constexpr int NBLOCKS = BS * CH * BPP;         // 1536

__global__ __launch_bounds__(STAT_THREADS) void stats_kernel(
    const float* __restrict__ x, double* __restrict__ sums) {
    const int plane = blockIdx.x / BPP;        // 0..95 = b*3+c
    const int blk   = blockIdx.x % BPP;
    const int c     = plane % CH;
    const float* __restrict__ base = x + (size_t)plane * HWSZ;
    const int tid = threadIdx.x;
    const int h0  = blk * ROWS_PER_BLK;

    float s1 = 0.f, s2 = 0.f, s3 = 0.f;

    for (int nb = 0; nb < NBATCH; ++nb) {
        float4 a[BATCH], p1[BATCH], p2[BATCH];
#pragma unroll
        for (int j = 0; j < BATCH; ++j) {
            const int idx  = tid + (nb * BATCH + j) * STAT_THREADS;
            const int r    = idx >> 7;
            const int col4 = idx & 127;
            const int o    = ((h0 + r) << 9) + (col4 << 2);
            const bool w0  = (col4 == 0);
            const int q1 = (HWSZ + 508 - o) & (HWSZ - 1);
            const int q2 = (HWSZ + (w0 ? 0 : 512) - o) & (HWSZ - 1);
            a[j]  = *reinterpret_cast<const float4*>(base + o);
            p1[j] = *reinterpret_cast<const float4*>(base + q1);
            p2[j] = *reinterpret_cast<const float4*>(base + q2);
        }
#pragma unroll
        for (int j = 0; j < BATCH; ++j) {
            const int idx = tid + (nb * BATCH + j) * STAT_THREADS;
            const int h   = h0 + (idx >> 7);
            const float4 a_ = a[j], p1_ = p1[j], p2_ = p2[j];
            const float asq = a_.x*a_.x + a_.y*a_.y + a_.z*a_.z + a_.w*a_.w;
            const float qsq = p1_.x*p1_.x + p1_.y*p1_.y + p1_.z*p1_.z + p1_.w*p1_.w;
            const float prd = a_.x*p2_.x + a_.y*p1_.w + a_.z*p1_.z + a_.w*p1_.y;
            const float two = (h == 0) ? 0.f : 1.f;
            s2 += asq + two * qsq;
            s3 += (h == 0 ? 1.f : 2.f) * prd;
            if (h == 0 && idx == 0) s1 += a_.x;
        }
    }

    // ---- row 256 tail (self-paired, factor 1) on blk 0 ----
    if (blk == 0 && tid < 128) {
        const int o  = 256 * WW + tid * 4;
        const bool w0 = (tid == 0);
        const int q1 = (HWSZ + 508 - o) & (HWSZ - 1);
        const int q2 = (HWSZ + (w0 ? 0 : 512) - o) & (HWSZ - 1);
        const float4 a_  = *reinterpret_cast<const float4*>(base + o);
        const float4 p1_ = *reinterpret_cast<const float4*>(base + q1);
        const float4 p2_ = *reinterpret_cast<const float4*>(base + q2);
        s2 += a_.x*a_.x + a_.y*a_.y + a_.z*a_.z + a_.w*a_.w;
        s3 += a_.x*p2_.x + a_.y*p1_.w + a_.z*p1_.z + a_.w*p1_.y;
    }

    // ---- wave reduce, cross-wave via LDS, 3 double atomics per block ----
#pragma unroll
    for (int off = 32; off > 0; off >>= 1) {
        s1 += __shfl_down(s1, off);
        s2 += __shfl_down(s2, off);
        s3 += __shfl_down(s3, off);
    }
    __shared__ float red[3][4];
    const int lane = tid & 63, wv = tid >> 6;
    if (lane == 0) { red[0][wv] = s1; red[1][wv] = s2; red[2][wv] = s3; }
    __syncthreads();
    if (tid == 0) {
        double t1 = 0.0, t2 = 0.0, t3 = 0.0;
#pragma unroll
        for (int j = 0; j < 4; ++j) {
            t1 += (double)red[0][j];
            t2 += (double)red[1][j];
            t3 += (double)red[2][j];
        }
        atomicAdd(&sums[c * 3 + 0], t1);
        atomicAdd(&sums[c * 3 + 1], t2);
        atomicAdd(&sums[c * 3 + 2], t3);
    }
}

// ---------------- normalize (finalize folded in, nt stores) ----------------
__global__ __launch_bounds__(256) void norm_kernel(
    const float* __restrict__ x, const double* __restrict__ sums,
    const float* __restrict__ gamma, const float* __restrict__ beta,
    const float* __restrict__ rmean, const float* __restrict__ rvar,
    float* __restrict__ out) {
    __shared__ float ssh[6];
    if (threadIdx.x < CH) {
        const int c = threadIdx.x;
        const double S1 = sums[c * 3 + 0];
        const double S2 = sums[c * 3 + 1];
        const double S3 = sums[c * 3 + 2];
        const double N = (double)BS * (double)HWSZ;
        const double mean = S1 / N;
        const double ex2  = (S2 + S3) / (2.0 * N * (double)HWSZ);
        const double var  = ex2 - mean * mean;
        const double rm = (double)rmean[c] * MOMENTUM + (1.0 - MOMENTUM) * mean;
        const double rv = (double)rvar[c]  * MOMENTUM + (1.0 - MOMENTUM) * var;
        const double inv_std = 1.0 / sqrt(rv + EPSILON);
        const float scale = (float)((double)gamma[c] * inv_std);
        const float shift = (float)((double)beta[c] - (double)scale * rm);
        ssh[c * 2 + 0] = scale;
        ssh[c * 2 + 1] = shift;
    }
    __syncthreads();
    float sc[CH], sh[CH];
#pragma unroll
    for (int c = 0; c < CH; ++c) { sc[c] = ssh[c * 2]; sh[c] = ssh[c * 2 + 1]; }
    const int n4 = BS * CH * HWSZ / 4;               // 6,291,456
    const int stride = gridDim.x * blockDim.x;
    for (int i4 = blockIdx.x * blockDim.x + threadIdx.x; i4 < n4; i4 += stride) {
        const int c = (i4 >> 16) % CH;               // 65536 f4 per plane
        const f32x4 v = *((const f32x4*)x + i4);
        const float s = sc[c], t = sh[c];
        f32x4 o;
        o.x = fmaf(v.x, s, t);
        o.y = fmaf(v.y, s, t);
        o.z = fmaf(v.z, s, t);
        o.w = fmaf(v.w, s, t);
        __builtin_nontemporal_store(o, (f32x4*)out + i4);
    }
}

extern "C" void kernel_launch(void* const* d_in, const int* in_sizes, int n_in,
                              void* d_out, int out_size, void* d_ws, size_t ws_size,
                              hipStream_t stream) {
    const float* x     = (const float*)d_in[0];
    const float* gamma = (const float*)d_in[1];
    const float* beta  = (const float*)d_in[2];
    const float* rmean = (const float*)d_in[3];
    const float* rvar  = (const float*)d_in[4];
    float* out = (float*)d_out;

    double* sums = (double*)d_ws;                    // 9 doubles

    hipMemsetAsync(d_ws, 0, 80, stream);
    stats_kernel<<<NBLOCKS, STAT_THREADS, 0, stream>>>(x, sums);
    norm_kernel<<<2048, 256, 0, stream>>>(x, sums, gamma, beta, rmean, rvar, out);
}

// Round 16
// 59.467 us; speedup vs baseline: 1.7928x; 1.7928x over previous
//
#include <hip/hip_runtime.h>
#include <math.h>

// Problem constants (from reference setup_inputs)
#define BS 32
#define CH 3
#define HH 512
#define WW 512
#define HWSZ (HH * WW)          // 262144
#define MOMENTUM 0.8
#define EPSILON 1e-5

// ---------------- stats kernel (r10-proven, best known) ----------------
// S1[c] = sum_b x[b,c,0,0]
// S2[c] = sum_{b,h,w} x^2
// S3[c] = sum_{b,h,w} x[h,w] * x[(-h)%H, (-w)%W]
//
// Index math (verified r8..r15): for aligned f4 at o, partners of o+1..o+3
// are .w,.z,.y of f4 at q1=(HWSZ+508-o)&mask; partner of o is .x of f4 at
// q2=(HWSZ+(w0?0:512)-o)&mask, w0=(o%512==0).
// Symmetry (verified r10): A-rows 0..255; h>=1 factor 2, partner-row s2 via
// p1^2; h==0 factor 1, no partner-square; row 256 self-paired tail (blk 0).
// HARD-WON RULES:
//  - lane-adjacent must stay address-adjacent (r14: per-thread runs = 1.6x WORSE)
//  - batch loads before consumption (r9: +30%), BATCH=4, interleaved idx
//  - per-block partials, NO same-address atomics (r15: 1536-block double-
//    atomic tail = +40us XCD line-bounce storm)
//  - grid 1536 for this body (r7: 3072 hurt the gather path)

constexpr int BPP = 16;
constexpr int ROWS_PER_BLK = 16;
constexpr int STAT_THREADS = 256;
constexpr int F4_PER_THREAD = ROWS_PER_BLK * (WW / 4) / STAT_THREADS;  // 8
constexpr int BATCH = 4;
constexpr int NBATCH = F4_PER_THREAD / BATCH;  // 2
constexpr int NBLOCKS = BS * CH * BPP;         // 1536

__global__ __launch_bounds__(STAT_THREADS) void stats_kernel(
    const float* __restrict__ x, float4* __restrict__ partials) {
    const int plane = blockIdx.x / BPP;        // 0..95 = b*3+c
    const int blk   = blockIdx.x % BPP;
    const float* __restrict__ base = x + (size_t)plane * HWSZ;
    const int tid = threadIdx.x;
    const int h0  = blk * ROWS_PER_BLK;

    float s1 = 0.f, s2 = 0.f, s3 = 0.f;

    for (int nb = 0; nb < NBATCH; ++nb) {
        float4 a[BATCH], p1[BATCH], p2[BATCH];
#pragma unroll
        for (int j = 0; j < BATCH; ++j) {
            const int idx  = tid + (nb * BATCH + j) * STAT_THREADS;
            const int r    = idx >> 7;
            const int col4 = idx & 127;
            const int o    = ((h0 + r) << 9) + (col4 << 2);
            const bool w0  = (col4 == 0);
            const int q1 = (HWSZ + 508 - o) & (HWSZ - 1);
            const int q2 = (HWSZ + (w0 ? 0 : 512) - o) & (HWSZ - 1);
            a[j]  = *reinterpret_cast<const float4*>(base + o);
            p1[j] = *reinterpret_cast<const float4*>(base + q1);
            p2[j] = *reinterpret_cast<const float4*>(base + q2);
        }
#pragma unroll
        for (int j = 0; j < BATCH; ++j) {
            const int idx = tid + (nb * BATCH + j) * STAT_THREADS;
            const int h   = h0 + (idx >> 7);
            const float4 a_ = a[j], p1_ = p1[j], p2_ = p2[j];
            const float asq = a_.x*a_.x + a_.y*a_.y + a_.z*a_.z + a_.w*a_.w;
            const float qsq = p1_.x*p1_.x + p1_.y*p1_.y + p1_.z*p1_.z + p1_.w*p1_.w;
            const float prd = a_.x*p2_.x + a_.y*p1_.w + a_.z*p1_.z + a_.w*p1_.y;
            const float two = (h == 0) ? 0.f : 1.f;
            s2 += asq + two * qsq;
            s3 += (h == 0 ? 1.f : 2.f) * prd;
            if (h == 0 && idx == 0) s1 += a_.x;
        }
    }

    // ---- row 256 tail (self-paired, factor 1) on blk 0 ----
    if (blk == 0 && tid < 128) {
        const int o  = 256 * WW + tid * 4;
        const bool w0 = (tid == 0);
        const int q1 = (HWSZ + 508 - o) & (HWSZ - 1);
        const int q2 = (HWSZ + (w0 ? 0 : 512) - o) & (HWSZ - 1);
        const float4 a_  = *reinterpret_cast<const float4*>(base + o);
        const float4 p1_ = *reinterpret_cast<const float4*>(base + q1);
        const float4 p2_ = *reinterpret_cast<const float4*>(base + q2);
        s2 += a_.x*a_.x + a_.y*a_.y + a_.z*a_.z + a_.w*a_.w;
        s3 += a_.x*p2_.x + a_.y*p1_.w + a_.z*p1_.z + a_.w*p1_.y;
    }

    // ---- wave reduce, cross-wave via LDS, per-block partial (NO atomics) ----
#pragma unroll
    for (int off = 32; off > 0; off >>= 1) {
        s1 += __shfl_down(s1, off);
        s2 += __shfl_down(s2, off);
        s3 += __shfl_down(s3, off);
    }
    __shared__ float red[3][4];
    const int lane = tid & 63, wv = tid >> 6;
    if (lane == 0) { red[0][wv] = s1; red[1][wv] = s2; red[2][wv] = s3; }
    __syncthreads();
    if (tid == 0) {
        float4 p;
        p.x = red[0][0] + red[0][1] + red[0][2] + red[0][3];
        p.y = red[1][0] + red[1][1] + red[1][2] + red[1][3];
        p.z = red[2][0] + red[2][1] + red[2][2] + red[2][3];
        p.w = 0.f;
        partials[blockIdx.x] = p;
    }
}

// ---------------- finalize: reduce partials, per-channel scale/shift ----------------
// one block per channel c; partials for c live at blockIdx = (b*CH+c)*BPP+blk
__global__ __launch_bounds__(256) void finalize_kernel(
    const float4* __restrict__ partials,
    const float* __restrict__ gamma, const float* __restrict__ beta,
    const float* __restrict__ rmean, const float* __restrict__ rvar,
    float* __restrict__ ss) {
    const int c = blockIdx.x;
    const int tid = threadIdx.x;
    const int per_c = BS * BPP;                // 512 partials per channel
    double t1 = 0.0, t2 = 0.0, t3 = 0.0;
    for (int k = tid; k < per_c; k += 256) {
        const int b = k / BPP, blk = k % BPP;
        const float4 p = partials[(b * CH + c) * BPP + blk];
        t1 += (double)p.x; t2 += (double)p.y; t3 += (double)p.z;
    }
#pragma unroll
    for (int off = 32; off > 0; off >>= 1) {
        t1 += __shfl_down(t1, off);
        t2 += __shfl_down(t2, off);
        t3 += __shfl_down(t3, off);
    }
    __shared__ double red[3][4];
    const int lane = tid & 63, wv = tid >> 6;
    if (lane == 0) { red[0][wv] = t1; red[1][wv] = t2; red[2][wv] = t3; }
    __syncthreads();
    if (tid == 0) {
        const double S1 = red[0][0] + red[0][1] + red[0][2] + red[0][3];
        const double S2 = red[1][0] + red[1][1] + red[1][2] + red[1][3];
        const double S3 = red[2][0] + red[2][1] + red[2][2] + red[2][3];
        const double N = (double)BS * (double)HWSZ;
        const double mean = S1 / N;
        const double ex2  = (S2 + S3) / (2.0 * N * (double)HWSZ);
        const double var  = ex2 - mean * mean;
        const double rm = (double)rmean[c] * MOMENTUM + (1.0 - MOMENTUM) * mean;
        const double rv = (double)rvar[c]  * MOMENTUM + (1.0 - MOMENTUM) * var;
        const double inv_std = 1.0 / sqrt(rv + EPSILON);
        const float scale = (float)((double)gamma[c] * inv_std);
        const float shift = (float)((double)beta[c] - (double)scale * rm);
        ss[c * 2 + 0] = scale;
        ss[c * 2 + 1] = shift;
    }
}

// ---------------- elementwise normalize ----------------
__global__ __launch_bounds__(256) void norm_kernel(
    const float* __restrict__ x, const float* __restrict__ ss,
    float* __restrict__ out) {
    float sc[CH], sh[CH];
#pragma unroll
    for (int c = 0; c < CH; ++c) { sc[c] = ss[c * 2]; sh[c] = ss[c * 2 + 1]; }
    const int n4 = BS * CH * HWSZ / 4;               // 6,291,456
    const int stride = gridDim.x * blockDim.x;
    for (int i4 = blockIdx.x * blockDim.x + threadIdx.x; i4 < n4; i4 += stride) {
        const int c = (i4 >> 16) % CH;               // 65536 f4 per plane
        const float4 v = reinterpret_cast<const float4*>(x)[i4];
        const float s = sc[c], t = sh[c];
        float4 o;
        o.x = fmaf(v.x, s, t);
        o.y = fmaf(v.y, s, t);
        o.z = fmaf(v.z, s, t);
        o.w = fmaf(v.w, s, t);
        reinterpret_cast<float4*>(out)[i4] = o;
    }
}

extern "C" void kernel_launch(void* const* d_in, const int* in_sizes, int n_in,
                              void* d_out, int out_size, void* d_ws, size_t ws_size,
                              hipStream_t stream) {
    const float* x     = (const float*)d_in[0];
    const float* gamma = (const float*)d_in[1];
    const float* beta  = (const float*)d_in[2];
    const float* rmean = (const float*)d_in[3];
    const float* rvar  = (const float*)d_in[4];
    float* out = (float*)d_out;

    float4* partials = (float4*)d_ws;                    // 1536 * 16B = 24 KiB
    float*  ss = (float*)((char*)d_ws + NBLOCKS * 16);   // 6 floats

    stats_kernel<<<NBLOCKS, STAT_THREADS, 0, stream>>>(x, partials);
    finalize_kernel<<<CH, 256, 0, stream>>>(partials, gamma, beta, rmean, rvar, ss);
    norm_kernel<<<2048, 256, 0, stream>>>(x, ss, out);
}